// Round 9
// baseline (120.953 us; speedup 1.0000x reference)
//
#include <hip/hip_runtime.h>

namespace {
constexpr int NB   = 16;
constexpr int NC   = 64;
constexpr int HW   = 128*128;
constexpr int SL   = 16384;
constexpr int CQ   = 64;
constexpr int NCH  = SL/CQ;   // 256

typedef short short8 __attribute__((ext_vector_type(8)));   // 8 bf16
typedef float f32x4  __attribute__((ext_vector_type(4)));

__device__ __forceinline__ float frcp(float x){ return __builtin_amdgcn_rcpf(x); }
__device__ __forceinline__ float rl(float v, int s){
  return __int_as_float(__builtin_amdgcn_readlane(__float_as_int(v), s));
}
__device__ __forceinline__ float sigu(float a){ return frcp(1.0f + __expf(-a)); }
__device__ __forceinline__ float softplusf(float a){
  return fmaxf(a, 0.f) + __logf(1.f + __expf(-fabsf(a)));
}
__device__ __forceinline__ unsigned bfr(float x){
  unsigned u = __float_as_uint(x);
  u = u + 0x7FFF + ((u>>16)&1);
  return u>>16;
}
__device__ __forceinline__ unsigned pk2(float a, float b){
  return (bfr(a)&0xFFFFu) | (bfr(b)<<16);
}
__device__ __forceinline__ float blo(unsigned u){ return __uint_as_float(u<<16); }
__device__ __forceinline__ float bhi(unsigned u){ return __uint_as_float(u & 0xFFFF0000u); }
union CV8 { unsigned u[4]; short8 s; };

__global__ __launch_bounds__(256) void k_tok(
    const float* __restrict__ x, const float* __restrict__ w_tok,
    const float* __restrict__ b_tok, float* __restrict__ g0)
{
  __shared__ float s_wt[NC][8];
  __shared__ float s_bt[8];
  for (int i = threadIdx.x; i < NC*8; i += 256) s_wt[i>>3][i&7] = w_tok[(i&7)*NC + (i>>3)];
  if (threadIdx.x < 8) s_bt[threadIdx.x] = b_tok[threadIdx.x];
  __syncthreads();
  long idx = (long)blockIdx.x * 256 + threadIdx.x;
  int b = (int)(idx >> 14);
  int l = (int)(idx & (SL-1));
  float acc[8];
  #pragma unroll
  for (int g = 0; g < 8; ++g) acc[g] = s_bt[g];
  const float* xp = x + (long)b*NC*HW + l;
  #pragma unroll 8
  for (int c = 0; c < NC; ++c) {
    float v = xp[(long)c*HW];
    const float4* wr = (const float4*)s_wt[c];
    float4 w0 = wr[0], w1 = wr[1];
    acc[0] += v*w0.x; acc[1] += v*w0.y; acc[2] += v*w0.z; acc[3] += v*w0.w;
    acc[4] += v*w1.x; acc[5] += v*w1.y; acc[6] += v*w1.z; acc[7] += v*w1.w;
  }
  float* gp = g0 + idx*8;
  *(float4*)gp     = make_float4(acc[0],acc[1],acc[2],acc[3]);
  *(float4*)(gp+4) = make_float4(acc[4],acc[5],acc[6],acc[7]);
}

// k_front: front-end ONCE per chunk + Sc/Pc + M + Y_intra(+D*x) to global.
__global__ __launch_bounds__(128) void k_front(
    const float* __restrict__ g0, const float* __restrict__ w_in,
    const float* __restrict__ w_conv, const float* __restrict__ b_conv,
    const float* __restrict__ dt_bias, const float* __restrict__ A_log,
    const float* __restrict__ Dvec,
    float* __restrict__ Sc, float* __restrict__ Pc,
    float* __restrict__ ceg, unsigned short* __restrict__ Cg,
    float* __restrict__ Yg)
{
  __shared__ float s_win[66][8];
  __shared__ float s_wc[48][4];
  __shared__ float s_misc[8];
  __shared__ char  s_big[2*10240];   // per wave: X' 2KB | Mb 8KB (BT/uB/uC overlay)

  int tid = threadIdx.x, lane = tid & 63, wave = tid >> 6;
  int c15 = lane & 15, lg = lane >> 4;

  for (int i = tid; i < 66*8; i += 128) s_win[i>>3][i&7] = w_in[i];
  if (tid < 48) {
    s_wc[tid][0] = w_conv[tid*3];   s_wc[tid][1] = w_conv[tid*3+1];
    s_wc[tid][2] = w_conv[tid*3+2]; s_wc[tid][3] = b_conv[tid];
  }
  if (tid < 2) {
    s_misc[tid]   = -__expf(A_log[tid]);
    s_misc[2+tid] = dt_bias[tid];
    s_misc[4+tid] = Dvec[tid];
  }
  __syncthreads();

  auto dot8 = [&](const float* uu, int row) -> float {
    const float4* wr = (const float4*)s_win[row];
    float4 w0 = wr[0], w1 = wr[1];
    return uu[0]*w0.x + uu[1]*w0.y + uu[2]*w0.z + uu[3]*w0.w
         + uu[4]*w1.x + uu[5]*w1.y + uu[6]*w1.z + uu[7]*w1.w;
  };

  int b   = blockIdx.x >> 7;               // 128 blocks/batch, 2 chunks/block
  int chB = (blockIdx.x & 127)*2 + wave;
  long cg = (long)b*NCH + chB;
  int l0  = chB*CQ;
  long pos = (long)b*SL + l0 + lane;
  char* WR = &s_big[wave*10240];
  char* xp = WR;            // X' bf16 [16][64] swizzled
  char* Mb = WR + 2048;     // 8KB: phase A holds BT/uB/uC, phase C holds M, D holds ytr
  char* BT = Mb;
  char* uB = Mb + 2048;
  char* uC = Mb + 4096;
  char* ceB = xp;           // overlays X' after Xf loads

  float u[8];
  { const float* up = g0 + pos*8;
    float4 a = *(const float4*)up, c = *(const float4*)(up+4);
    u[0]=a.x;u[1]=a.y;u[2]=a.z;u[3]=a.w;u[4]=c.x;u[5]=c.y;u[6]=c.z;u[7]=c.w; }

  // ---- halo pre-values ----
  float hA, hB = 0.f;
  {
    int pA = lane >> 5, jA = lane & 31;
    int hlA = l0 - 2 + pA;
    bool okA = (hlA >= 0);
    const float* hp2 = g0 + ((long)b*SL + (okA ? hlA : 0))*8;
    float4 a = *(const float4*)hp2, c = *(const float4*)(hp2+4);
    float uA[8] = {a.x,a.y,a.z,a.w,c.x,c.y,c.z,c.w};
    hA = okA ? dot8(uA, 16+jA) : 0.f;
    int pB = (lane >> 4) & 1, jB = 32 + (lane & 15);
    int hlB = l0 - 2 + pB;
    bool okB = (hlB >= 0);
    const float* hq = g0 + ((long)b*SL + (okB ? hlB : 0))*8;
    float4 a2 = *(const float4*)hq, c2 = *(const float4*)(hq+4);
    float uB8[8] = {a2.x,a2.y,a2.z,a2.w,c2.x,c2.y,c2.z,c2.w};
    hB = okB ? dot8(uB8, 16+jB) : 0.f;
  }

  // ---- in-proj + conv + silu ----
  float xv[16], Bv[16], Cr[16];
  #pragma unroll
  for (int jb = 0; jb < 6; ++jb) {
    float pr[8];
    #pragma unroll
    for (int jj = 0; jj < 8; ++jj) pr[jj] = dot8(u, 16 + jb*8 + jj);
    #pragma unroll
    for (int jj = 0; jj < 8; ++jj) {
      int j = jb*8 + jj;
      float pm1 = __shfl_up(pr[jj], 1);
      float pm2 = __shfl_up(pr[jj], 2);
      float h0j = (j < 32) ? rl(hA, j)      : rl(hB, j-32);
      float h1j = (j < 32) ? rl(hA, 32+j)   : rl(hB, 16+(j-32));
      pm1 = (lane == 0) ? h1j : pm1;
      pm2 = (lane == 0) ? h0j : ((lane == 1) ? h1j : pm2);
      float4 wc = *(const float4*)s_wc[j];
      float a = wc.w + pm2*wc.x + pm1*wc.y + pr[jj]*wc.z;
      float s = a * sigu(a);
      if (j < 16) xv[j] = s;
      else if (j < 32) Bv[j-16] = s;
      else Cr[j-32] = s;
    }
  }

  // ---- dt + cumsum ----
  float dt0 = softplusf(dot8(u, 64) + s_misc[2]);
  float dt1 = softplusf(dot8(u, 65) + s_misc[3]);
  float c0 = s_misc[0]*dt0, c1 = s_misc[1]*dt1;
  #pragma unroll
  for (int off = 1; off < 64; off <<= 1) {
    float t0 = __shfl_up(c0, off), t1 = __shfl_up(c1, off);
    if (lane >= off) { c0 += t0; c1 += t1; }
  }
  float ce0 = __expf(c0), ce1 = __expf(c1);
  float cf0 = __expf(-c0)*dt0, cf1 = __expf(-c1)*dt1;
  float cee0 = rl(ce0, 63), cee1 = rl(ce1, 63);

  // ---- early global stores (overlap with MFMA phases) ----
  ceg[cg*128 + lane]      = ce0;
  ceg[cg*128 + 64 + lane] = ce1;
  { CV8 w;
    w.u[0]=pk2(Cr[0],Cr[1]);  w.u[1]=pk2(Cr[2],Cr[3]);
    w.u[2]=pk2(Cr[4],Cr[5]);  w.u[3]=pk2(Cr[6],Cr[7]);
    *(short8*)(Cg + cg*1024 + lane*16) = w.s;
    w.u[0]=pk2(Cr[8],Cr[9]);  w.u[1]=pk2(Cr[10],Cr[11]);
    w.u[2]=pk2(Cr[12],Cr[13]);w.u[3]=pk2(Cr[14],Cr[15]);
    *(short8*)(Cg + cg*1024 + lane*16 + 8) = w.s;
  }
  if (lane == 0) { Pc[cg*2] = cee0; Pc[cg*2+1] = cee1; }

  // ---- LDS slabs: X', BT, uB, uC ----
  #pragma unroll
  for (int hp = 0; hp < 16; ++hp) {
    float cfh = (hp < 8) ? cf0 : cf1;
    *(short*)(xp + hp*128 + ((lane*2) ^ ((hp&7)<<4))) = (short)bfr(cfh*xv[hp]);
  }
  #pragma unroll
  for (int n = 0; n < 16; ++n)
    *(short*)(BT + n*128 + ((lane*2) ^ ((n&7)<<4))) = (short)bfr(Bv[n]);
  { CV8 w;
    w.u[0]=pk2(Bv[0],Bv[1]);  w.u[1]=pk2(Bv[2],Bv[3]);
    w.u[2]=pk2(Bv[4],Bv[5]);  w.u[3]=pk2(Bv[6],Bv[7]);
    *(short8*)(uB + lane*32) = w.s;
    w.u[0]=pk2(Bv[8],Bv[9]);  w.u[1]=pk2(Bv[10],Bv[11]);
    w.u[2]=pk2(Bv[12],Bv[13]);w.u[3]=pk2(Bv[14],Bv[15]);
    *(short8*)(uB + lane*32 + 16) = w.s;
    w.u[0]=pk2(Cr[0],Cr[1]);  w.u[1]=pk2(Cr[2],Cr[3]);
    w.u[2]=pk2(Cr[4],Cr[5]);  w.u[3]=pk2(Cr[6],Cr[7]);
    *(short8*)(uC + lane*32) = w.s;
    w.u[0]=pk2(Cr[8],Cr[9]);  w.u[1]=pk2(Cr[10],Cr[11]);
    w.u[2]=pk2(Cr[12],Cr[13]);w.u[3]=pk2(Cr[14],Cr[15]);
    *(short8*)(uC + lane*32 + 16) = w.s;
  }
  __builtin_amdgcn_wave_barrier();
  __builtin_amdgcn_sched_barrier(0x7F);

  // ---- Sc MFMA ----
  short8 zero8 = {0,0,0,0,0,0,0,0};
  f32x4  zero4 = {0.f,0.f,0.f,0.f};
  { f32x4 sacc = zero4;
    #pragma unroll
    for (int kb = 0; kb < 2; ++kb) {
      int cb = (64*kb + 16*lg) ^ ((c15&7)<<4);
      short8 Af = *(const short8*)(xp + c15*128 + cb);
      short8 Bf = *(const short8*)(BT + c15*128 + cb);
      sacc = __builtin_amdgcn_mfma_f32_16x16x32_bf16(Af, Bf, sacc, 0, 0, 0);
    }
    float cee = (lg < 2) ? cee0 : cee1;
    #pragma unroll
    for (int r = 0; r < 4; ++r)
      Sc[cg*256 + (4*lg+r)*16 + c15] = cee*sacc[r];
  }

  // ---- fragments ----
  short8 Cfr[4], Bfr[4], Xf[2];
  #pragma unroll
  for (int tt = 0; tt < 4; ++tt) {
    Cfr[tt] = zero8; Bfr[tt] = zero8;
    if (lg < 2) {
      Cfr[tt] = *(const short8*)(uC + (16*tt + c15)*32 + 16*lg);
      Bfr[tt] = *(const short8*)(uB + (16*tt + c15)*32 + 16*lg);
    }
  }
  #pragma unroll
  for (int kb = 0; kb < 2; ++kb)
    Xf[kb] = *(const short8*)(xp + c15*128 + ((64*kb + 16*lg) ^ ((c15&7)<<4)));
  __builtin_amdgcn_wave_barrier();
  __builtin_amdgcn_sched_barrier(0x7F);

  // ---- G' = B.C^T, mask, write M (bf16 swizzled) ; ceB ----
  #pragma unroll
  for (int tt = 0; tt < 4; ++tt) {
    int t  = 16*tt + c15;
    int sw = (t&7)<<4;
    #pragma unroll
    for (int ts = 0; ts < 4; ++ts) {
      if (ts <= tt) {
        f32x4 gA = __builtin_amdgcn_mfma_f32_16x16x32_bf16(Bfr[ts], Cfr[tt], zero4, 0,0,0);
        if (ts == tt) {
          #pragma unroll
          for (int r = 0; r < 4; ++r)
            gA[r] = (4*lg + r <= c15) ? gA[r] : 0.f;
        }
        uint2 wv; wv.x = pk2(gA[0],gA[1]); wv.y = pk2(gA[2],gA[3]);
        *(uint2*)(Mb + t*128 + ((32*ts + 8*lg) ^ sw)) = wv;
      }
    }
    if (tt == 0 || tt == 2) {
      uint2 zv; zv.x = 0u; zv.y = 0u;
      *(uint2*)(Mb + t*128 + ((32*(tt+1) + 8*lg) ^ sw)) = zv;
    }
  }
  *(float*)(ceB + lane*4)       = ce0;
  *(float*)(ceB + 256 + lane*4) = ce1;
  __builtin_amdgcn_wave_barrier();
  __builtin_amdgcn_sched_barrier(0x7F);

  // ---- Y_intra = M . X' ----
  f32x4 acc[4];
  #pragma unroll
  for (int tt = 0; tt < 4; ++tt) acc[tt] = zero4;
  #pragma unroll
  for (int tt = 0; tt < 4; ++tt) {
    int t = 16*tt + c15, sw = (t&7)<<4;
    {
      short8 Mf = *(const short8*)(Mb + t*128 + ((16*lg) ^ sw));
      acc[tt] = __builtin_amdgcn_mfma_f32_16x16x32_bf16(Mf, Xf[0], acc[tt], 0,0,0);
    }
    if (tt >= 2) {
      short8 Mf = *(const short8*)(Mb + t*128 + ((64 + 16*lg) ^ sw));
      acc[tt] = __builtin_amdgcn_mfma_f32_16x16x32_bf16(Mf, Xf[1], acc[tt], 0,0,0);
    }
  }
  // ce merge -> ytr (reuse Mb region: all Mf reads precede in program order)
  char* ytr = Mb;   // f32 [64][24], rows 96B
  int hh = (c15 < 8) ? 0 : 1;
  #pragma unroll
  for (int tt = 0; tt < 4; ++tt) {
    float4 cev = *(const float4*)(ceB + hh*256 + (16*tt + 4*lg)*4);
    float cva[4] = {cev.x, cev.y, cev.z, cev.w};
    #pragma unroll
    for (int r = 0; r < 4; ++r)
      *(float*)(ytr + (16*tt + 4*lg + r)*96 + c15*4) = cva[r]*acc[tt][r];
  }
  __builtin_amdgcn_wave_barrier();
  __builtin_amdgcn_sched_barrier(0x7F);

  // ---- rows out: + D*x, store Yg (coalesced 64B/lane) ----
  float D0 = s_misc[4], D1 = s_misc[5];
  float yr[16];
  #pragma unroll
  for (int i = 0; i < 4; ++i) {
    float4 q = *(const float4*)(ytr + lane*96 + 16*i);
    yr[4*i] = q.x; yr[4*i+1] = q.y; yr[4*i+2] = q.z; yr[4*i+3] = q.w;
  }
  #pragma unroll
  for (int d = 0; d < 16; ++d) yr[d] += ((d < 8) ? D0 : D1)*xv[d];
  float* yg = Yg + cg*1024 + lane*16;
  *(float4*)(yg)    = make_float4(yr[0],yr[1],yr[2],yr[3]);
  *(float4*)(yg+4)  = make_float4(yr[4],yr[5],yr[6],yr[7]);
  *(float4*)(yg+8)  = make_float4(yr[8],yr[9],yr[10],yr[11]);
  *(float4*)(yg+12) = make_float4(yr[12],yr[13],yr[14],yr[15]);
}

__global__ __launch_bounds__(256) void k_scan(
    const float* __restrict__ Sc, const float* __restrict__ Pc,
    float* __restrict__ Stin)
{
  int b = blockIdx.x;
  int tid = threadIdx.x;           // hp*16 + n
  int h = tid >> 7;
  float st = 0.f;
  long base = (long)b * NCH;
  #pragma unroll 8
  for (int c = 0; c < NCH; ++c) {
    Stin[(base + c)*256 + tid] = st;
    st = st * Pc[(base + c)*2 + h] + Sc[(base + c)*256 + tid];
  }
}

// k_apply: y = Yg + ce*(C . St^T), then gate/RMS/out-proj/residual -> gf.
__global__ __launch_bounds__(256) void k_apply(
    const float* __restrict__ g0, const float* __restrict__ w_in,
    const float* __restrict__ norm_w, const float* __restrict__ w_out,
    const float* __restrict__ Stin, const float* __restrict__ ceg,
    const unsigned short* __restrict__ Cg, const float* __restrict__ Yg,
    float* __restrict__ gf)
{
  __shared__ float s_win[16][8];
  __shared__ float s_wout[8][16];
  __shared__ float s_nw[16];
  __shared__ float s_st[4][256];

  int tid = threadIdx.x, lane = tid & 63, wave = tid >> 6;
  if (tid < 128) s_win[tid>>3][tid&7] = w_in[tid];
  if (tid < 128) s_wout[tid>>4][tid&15] = w_out[tid];
  if (tid < 16)  s_nw[tid] = norm_w[tid];
  __syncthreads();

  auto dot8 = [&](const float* uu, int row) -> float {
    const float4* wr = (const float4*)s_win[row];
    float4 w0 = wr[0], w1 = wr[1];
    return uu[0]*w0.x + uu[1]*w0.y + uu[2]*w0.z + uu[3]*w0.w
         + uu[4]*w1.x + uu[5]*w1.y + uu[6]*w1.z + uu[7]*w1.w;
  };

  int b   = blockIdx.x >> 6;
  int chB = (blockIdx.x & 63)*4 + wave;
  long cg = (long)b*NCH + chB;
  long pos = (long)b*SL + chB*CQ + lane;

  // stage incoming state (1KB/wave)
  { float4 t4 = *(const float4*)(Stin + cg*256 + lane*4);
    *(float4*)&s_st[wave][lane*4] = t4; }

  float u[8];
  { const float* up = g0 + pos*8;
    float4 a = *(const float4*)up, c = *(const float4*)(up+4);
    u[0]=a.x;u[1]=a.y;u[2]=a.z;u[3]=a.w;u[4]=c.x;u[5]=c.y;u[6]=c.z;u[7]=c.w; }

  float Cr[16];
  { const uint4* cp = (const uint4*)(Cg + cg*1024 + lane*16);
    uint4 ca = cp[0], cb = cp[1];
    Cr[0]=blo(ca.x); Cr[1]=bhi(ca.x); Cr[2]=blo(ca.y); Cr[3]=bhi(ca.y);
    Cr[4]=blo(ca.z); Cr[5]=bhi(ca.z); Cr[6]=blo(ca.w); Cr[7]=bhi(ca.w);
    Cr[8]=blo(cb.x); Cr[9]=bhi(cb.x); Cr[10]=blo(cb.y); Cr[11]=bhi(cb.y);
    Cr[12]=blo(cb.z); Cr[13]=bhi(cb.z); Cr[14]=blo(cb.w); Cr[15]=bhi(cb.w); }

  float yr[16];
  { const float* yp = Yg + cg*1024 + lane*16;
    #pragma unroll
    for (int i = 0; i < 4; ++i) {
      float4 q = *(const float4*)(yp + 4*i);
      yr[4*i]=q.x; yr[4*i+1]=q.y; yr[4*i+2]=q.z; yr[4*i+3]=q.w;
    } }
  float ce0t = ceg[cg*128 + lane];
  float ce1t = ceg[cg*128 + 64 + lane];

  __builtin_amdgcn_wave_barrier();
  __builtin_amdgcn_sched_barrier(0x7F);

  // state contribution
  const float* st = &s_st[wave][0];
  float y[16];
  #pragma unroll
  for (int hp = 0; hp < 16; ++hp) {
    const float4* sp = (const float4*)(st + hp*16);
    float4 s0 = sp[0], s1 = sp[1], s2 = sp[2], s3 = sp[3];
    float a = Cr[0]*s0.x + Cr[1]*s0.y + Cr[2]*s0.z + Cr[3]*s0.w
            + Cr[4]*s1.x + Cr[5]*s1.y + Cr[6]*s1.z + Cr[7]*s1.w
            + Cr[8]*s2.x + Cr[9]*s2.y + Cr[10]*s2.z + Cr[11]*s2.w
            + Cr[12]*s3.x + Cr[13]*s3.y + Cr[14]*s3.z + Cr[15]*s3.w;
    y[hp] = yr[hp] + ((hp < 8) ? ce0t : ce1t)*a;
  }

  // gate, RMS norm, out-proj, +u residual
  float yv[16]; float ss = 0.f;
  #pragma unroll
  for (int d = 0; d < 16; ++d) {
    float zz = dot8(u, d);
    float v = y[d] * (zz * sigu(zz));
    yv[d] = v; ss += v*v;
  }
  float scn = rsqrtf(ss*(1.f/16.f) + 1e-5f);
  { const float4* nw = (const float4*)s_nw;
    float4 n0 = nw[0], n1 = nw[1], n2 = nw[2], n3 = nw[3];
    yv[0]*=scn*n0.x; yv[1]*=scn*n0.y; yv[2]*=scn*n0.z; yv[3]*=scn*n0.w;
    yv[4]*=scn*n1.x; yv[5]*=scn*n1.y; yv[6]*=scn*n1.z; yv[7]*=scn*n1.w;
    yv[8]*=scn*n2.x; yv[9]*=scn*n2.y; yv[10]*=scn*n2.z; yv[11]*=scn*n2.w;
    yv[12]*=scn*n3.x; yv[13]*=scn*n3.y; yv[14]*=scn*n3.z; yv[15]*=scn*n3.w; }
  float og[8];
  #pragma unroll
  for (int g = 0; g < 8; ++g) {
    const float4* wr = (const float4*)s_wout[g];
    float4 w0 = wr[0], w1 = wr[1], w2 = wr[2], w3 = wr[3];
    float a = u[g];
    a += yv[0]*w0.x + yv[1]*w0.y + yv[2]*w0.z + yv[3]*w0.w;
    a += yv[4]*w1.x + yv[5]*w1.y + yv[6]*w1.z + yv[7]*w1.w;
    a += yv[8]*w2.x + yv[9]*w2.y + yv[10]*w2.z + yv[11]*w2.w;
    a += yv[12]*w3.x + yv[13]*w3.y + yv[14]*w3.z + yv[15]*w3.w;
    og[g] = a;
  }
  float* gp = gf + pos*8;
  *(float4*)gp     = make_float4(og[0],og[1],og[2],og[3]);
  *(float4*)(gp+4) = make_float4(og[4],og[5],og[6],og[7]);
}

__global__ __launch_bounds__(256) void k_detok(
    const float* __restrict__ x, const float* __restrict__ gf,
    const float* __restrict__ w_detok, const float* __restrict__ b_detok,
    float* __restrict__ out)
{
  __shared__ float s_wd[NC][8];
  __shared__ float s_bd[NC];
  for (int i = threadIdx.x; i < NC*8; i += 256) s_wd[i>>3][i&7] = w_detok[i];
  if (threadIdx.x < NC) s_bd[threadIdx.x] = b_detok[threadIdx.x];
  __syncthreads();
  long idx = (long)blockIdx.x * 256 + threadIdx.x;
  int b = (int)(idx >> 14);
  int l = (int)(idx & (SL-1));
  float gv[8];
  const float* gp = gf + idx*8;
  { float4 a = *(const float4*)gp, c = *(const float4*)(gp+4);
    gv[0]=a.x;gv[1]=a.y;gv[2]=a.z;gv[3]=a.w;gv[4]=c.x;gv[5]=c.y;gv[6]=c.z;gv[7]=c.w; }
  const float* xp = x + (long)b*NC*HW + l;
  float* op = out + (long)b*NC*HW + l;
  #pragma unroll 4
  for (int c = 0; c < NC; ++c) {
    const float4* wr = (const float4*)s_wd[c];
    float4 w0 = wr[0], w1 = wr[1];
    float a = s_bd[c] + xp[(long)c*HW];
    a += gv[0]*w0.x + gv[1]*w0.y + gv[2]*w0.z + gv[3]*w0.w;
    a += gv[4]*w1.x + gv[5]*w1.y + gv[6]*w1.z + gv[7]*w1.w;
    op[(long)c*HW] = a;
  }
}
} // namespace

extern "C" void kernel_launch(void* const* d_in, const int* in_sizes, int n_in,
                              void* d_out, int out_size, void* d_ws, size_t ws_size,
                              hipStream_t stream)
{
  const float* x       = (const float*)d_in[0];
  const float* w_tok   = (const float*)d_in[1];
  const float* b_tok   = (const float*)d_in[2];
  const float* w_detok = (const float*)d_in[3];
  const float* b_detok = (const float*)d_in[4];
  const float* w_in    = (const float*)d_in[5];
  const float* w_conv  = (const float*)d_in[6];
  const float* b_conv  = (const float*)d_in[7];
  const float* dt_bias = (const float*)d_in[8];
  const float* A_log   = (const float*)d_in[9];
  const float* Dvec    = (const float*)d_in[10];
  const float* norm_w  = (const float*)d_in[11];
  const float* w_out   = (const float*)d_in[12];
  float* out = (float*)d_out;

  float* ws   = (float*)d_ws;
  float* g0   = ws;                          // 2,097,152 f
  float* gf   = g0 + (long)NB*SL*8;          // 2,097,152 f
  float* Sc   = gf + (long)NB*SL*8;          // 1,048,576 f
  float* Pc   = Sc + (long)NB*NCH*256;       // 8,192 f
  float* Stin = Pc + (long)NB*NCH*2;         // 1,048,576 f
  float* ceg  = Stin + (long)NB*NCH*256;     // 524,288 f
  float* Yg   = ceg + (long)NB*NCH*128;      // 4,194,304 f
  unsigned short* Cg = (unsigned short*)(Yg + (long)NB*NCH*1024);  // 8 MB
  // total ~50 MB

  k_tok<<<NB*SL/256, 256, 0, stream>>>(x, w_tok, b_tok, g0);
  k_front<<<NB*NCH/2, 128, 0, stream>>>(g0, w_in, w_conv, b_conv, dt_bias,
                                        A_log, Dvec, Sc, Pc, ceg, Cg, Yg);
  k_scan<<<NB, 256, 0, stream>>>(Sc, Pc, Stin);
  k_apply<<<NB*NCH/4, 256, 0, stream>>>(g0, w_in, norm_w, w_out,
                                        Stin, ceg, Cg, Yg, gf);
  k_detok<<<NB*SL/256, 256, 0, stream>>>(x, gf, w_detok, b_detok, out);
}

// Round 10
// 101.882 us; speedup vs baseline: 1.1872x; 1.1872x over previous
//
#include <hip/hip_runtime.h>

namespace {
constexpr int NB   = 16;
constexpr int NC   = 64;
constexpr int HW   = 128*128;
constexpr int SL   = 16384;
constexpr int CQ   = 64;
constexpr int NCH  = SL/CQ;   // 256
constexpr int PWV  = 11776;   // per-wave LDS bytes in k_front

typedef short short8 __attribute__((ext_vector_type(8)));   // 8 bf16
typedef float f32x4  __attribute__((ext_vector_type(4)));

__device__ __forceinline__ float frcp(float x){ return __builtin_amdgcn_rcpf(x); }
__device__ __forceinline__ float rl(float v, int s){
  return __int_as_float(__builtin_amdgcn_readlane(__float_as_int(v), s));
}
__device__ __forceinline__ float sigu(float a){ return frcp(1.0f + __expf(-a)); }
__device__ __forceinline__ float softplusf(float a){
  return fmaxf(a, 0.f) + __logf(1.f + __expf(-fabsf(a)));
}
__device__ __forceinline__ unsigned bfr(float x){
  unsigned u = __float_as_uint(x);
  u = u + 0x7FFF + ((u>>16)&1);
  return u>>16;
}
__device__ __forceinline__ unsigned pk2(float a, float b){
  return (bfr(a)&0xFFFFu) | (bfr(b)<<16);
}
__device__ __forceinline__ float blo(unsigned u){ return __uint_as_float(u<<16); }
__device__ __forceinline__ float bhi(unsigned u){ return __uint_as_float(u & 0xFFFF0000u); }
union CV8 { unsigned u[4]; short8 s; };

__global__ __launch_bounds__(256) void k_tok(
    const float* __restrict__ x, const float* __restrict__ w_tok,
    const float* __restrict__ b_tok, float* __restrict__ g0)
{
  __shared__ float s_wt[NC][8];
  __shared__ float s_bt[8];
  for (int i = threadIdx.x; i < NC*8; i += 256) s_wt[i>>3][i&7] = w_tok[(i&7)*NC + (i>>3)];
  if (threadIdx.x < 8) s_bt[threadIdx.x] = b_tok[threadIdx.x];
  __syncthreads();
  long idx = (long)blockIdx.x * 256 + threadIdx.x;
  int b = (int)(idx >> 14);
  int l = (int)(idx & (SL-1));
  float acc[8];
  #pragma unroll
  for (int g = 0; g < 8; ++g) acc[g] = s_bt[g];
  const float* xp = x + (long)b*NC*HW + l;
  #pragma unroll 8
  for (int c = 0; c < NC; ++c) {
    float v = xp[(long)c*HW];
    const float4* wr = (const float4*)s_wt[c];
    float4 w0 = wr[0], w1 = wr[1];
    acc[0] += v*w0.x; acc[1] += v*w0.y; acc[2] += v*w0.z; acc[3] += v*w0.w;
    acc[4] += v*w1.x; acc[5] += v*w1.y; acc[6] += v*w1.z; acc[7] += v*w1.w;
  }
  float* gp = g0 + idx*8;
  *(float4*)gp     = make_float4(acc[0],acc[1],acc[2],acc[3]);
  *(float4*)(gp+4) = make_float4(acc[4],acc[5],acc[6],acc[7]);
}

// k_front: fused (conv ∘ in-proj) via MFMA with effective weights, then
// Sc/Pc + masked decay matrix M + Y_intra (+D*x), all per-chunk, one wave/chunk.
__global__ __launch_bounds__(256) void k_front(
    const float* __restrict__ g0, const float* __restrict__ w_in,
    const float* __restrict__ w_conv, const float* __restrict__ b_conv,
    const float* __restrict__ dt_bias, const float* __restrict__ A_log,
    const float* __restrict__ Dvec,
    float* __restrict__ Sc, float* __restrict__ Pc,
    float* __restrict__ ceg, unsigned short* __restrict__ Cg,
    float* __restrict__ Yg)
{
  __shared__ short s_weff[64*32];   // [j][k] bf16: j<48 conv, 48..49 dt, rest 0
  __shared__ float s_bc[48];
  __shared__ float s_misc[8];       // A0,A1,dtb0,dtb1,D0,D1
  __shared__ char  s_wv[4][PWV];
  // per-wave offsets: BT 0..2K | uB 2K..4K | uC 4K..6K | (M overlays 0..8K,
  // ytr overlays 0..6K) | X' 8K..10K | dtL 10240 | cfL 10752 | ceL 11264

  int tid = threadIdx.x, lane = tid & 63, wave = tid >> 6;
  int c15 = lane & 15, lg = lane >> 4;

  for (int i = tid; i < 64*32; i += 256) {
    int j = i >> 5, k = i & 31;
    float v = 0.f;
    if (j < 48) {
      if (k < 24) v = w_conv[j*3 + (k>>3)] * w_in[(16+j)*8 + (k&7)];
    } else if (j < 50) {
      if (k >= 16 && k < 24) v = w_in[(64 + (j-48))*8 + (k-16)];
    }
    s_weff[i] = (short)bfr(v);
  }
  if (tid < 48) s_bc[tid] = b_conv[tid];
  if (tid < 2) {
    s_misc[tid]   = -__expf(A_log[tid]);
    s_misc[2+tid] = dt_bias[tid];
    s_misc[4+tid] = Dvec[tid];
  }
  __syncthreads();

  int b   = blockIdx.x >> 6;                 // 64 blocks/batch, 4 chunks/block
  int chB = (blockIdx.x & 63)*4 + wave;
  long cg = (long)b*NCH + chB;
  int l0  = chB*CQ;
  char* WR = s_wv[wave];
  char* BT  = WR;
  char* uB  = WR + 2048;
  char* uC  = WR + 4096;
  char* Mb  = WR;          // overlay after BT/uB/uC consumed
  char* ytr = WR;          // overlay after M consumed ([64][24] f32)
  char* Xp  = WR + 8192;
  char* dtL = WR + 10240;  // f32 [2][64]
  char* cfL = WR + 10752;  // f32 [2][64]
  char* ceL = WR + 11264;  // f32 [2][64]

  short8 zero8 = {0,0,0,0,0,0,0,0};
  f32x4  zero4 = {0.f,0.f,0.f,0.f};

  // ---- A-fragments: rows t = 16tt+c15, k = lg*8+g -> u[t-2+lg][g] ----
  short8 Af[4];
  #pragma unroll
  for (int tt = 0; tt < 4; ++tt) {
    int p = l0 + 16*tt + c15 - 2 + lg;
    bool ok = (lg < 3) && (p >= 0);
    const float* up = g0 + ((long)b*SL + (ok ? p : 0))*8;
    float4 a = *(const float4*)up, c = *(const float4*)(up+4);
    CV8 w;
    w.u[0] = pk2(a.x,a.y); w.u[1] = pk2(a.z,a.w);
    w.u[2] = pk2(c.x,c.y); w.u[3] = pk2(c.z,c.w);
    Af[tt] = ok ? w.s : zero8;
  }

  // ---- fused in-proj+conv MFMAs, per col-tile jj ----
  f32x4 xg[4];
  #pragma unroll
  for (int jj = 0; jj < 4; ++jj) {
    short8 Wf = *(const short8*)(s_weff + (16*jj + c15)*32 + lg*8);
    f32x4 o[4];
    #pragma unroll
    for (int tt = 0; tt < 4; ++tt)
      o[tt] = __builtin_amdgcn_mfma_f32_16x16x32_bf16(Af[tt], Wf, zero4, 0,0,0);
    if (jj == 3) {
      if (c15 < 2) {
        float bias = s_misc[2+c15];
        #pragma unroll
        for (int tt = 0; tt < 4; ++tt) {
          #pragma unroll
          for (int r = 0; r < 4; ++r)
            *(float*)(dtL + c15*256 + (16*tt + 4*lg + r)*4) = o[tt][r] + bias;
        }
      }
    } else {
      float bias = s_bc[16*jj + c15];
      #pragma unroll
      for (int tt = 0; tt < 4; ++tt) {
        float s0 = (o[tt][0]+bias), s1 = (o[tt][1]+bias);
        float s2 = (o[tt][2]+bias), s3 = (o[tt][3]+bias);
        s0 *= sigu(s0); s1 *= sigu(s1); s2 *= sigu(s2); s3 *= sigu(s3);
        int t0 = 16*tt + 4*lg;
        if (jj == 0) {
          f32x4 v; v[0]=s0; v[1]=s1; v[2]=s2; v[3]=s3;
          xg[tt] = v;
        } else if (jj == 1) {
          uint2 wv; wv.x = pk2(s0,s1); wv.y = pk2(s2,s3);
          *(uint2*)(BT + c15*128 + ((t0*2) ^ ((c15&7)<<4))) = wv;
          *(short*)(uB + (t0  )*32 + c15*2) = (short)bfr(s0);
          *(short*)(uB + (t0+1)*32 + c15*2) = (short)bfr(s1);
          *(short*)(uB + (t0+2)*32 + c15*2) = (short)bfr(s2);
          *(short*)(uB + (t0+3)*32 + c15*2) = (short)bfr(s3);
        } else {
          *(short*)(uC + (t0  )*32 + c15*2) = (short)bfr(s0);
          *(short*)(uC + (t0+1)*32 + c15*2) = (short)bfr(s1);
          *(short*)(uC + (t0+2)*32 + c15*2) = (short)bfr(s2);
          *(short*)(uC + (t0+3)*32 + c15*2) = (short)bfr(s3);
        }
      }
    }
  }
  __builtin_amdgcn_wave_barrier();
  __builtin_amdgcn_sched_barrier(0x7F);

  // ---- dt softplus + prefix cumsum (per lane = t) ----
  float dt0 = softplusf(*(const float*)(dtL + lane*4));
  float dt1 = softplusf(*(const float*)(dtL + 256 + lane*4));
  float c0 = s_misc[0]*dt0, c1 = s_misc[1]*dt1;
  #pragma unroll
  for (int off = 1; off < 64; off <<= 1) {
    float t0 = __shfl_up(c0, off), t1 = __shfl_up(c1, off);
    if (lane >= off) { c0 += t0; c1 += t1; }
  }
  float ce0 = __expf(c0), ce1 = __expf(c1);
  float cf0 = __expf(-c0)*dt0, cf1 = __expf(-c1)*dt1;
  float cee0 = rl(ce0, 63), cee1 = rl(ce1, 63);
  ceg[cg*128 + lane]      = ce0;
  ceg[cg*128 + 64 + lane] = ce1;
  if (lane == 0) { Pc[cg*2] = cee0; Pc[cg*2+1] = cee1; }
  *(float*)(cfL + lane*4)       = cf0;
  *(float*)(cfL + 256 + lane*4) = cf1;
  *(float*)(ceL + lane*4)       = ce0;
  *(float*)(ceL + 256 + lane*4) = ce1;
  __builtin_amdgcn_wave_barrier();
  __builtin_amdgcn_sched_barrier(0x7F);

  // ---- X' slab: X'[hp=c15][t] = cf_h[t]*x[t][hp], bf16 swizzled ----
  int hh = (c15 < 8) ? 0 : 1;
  #pragma unroll
  for (int tt = 0; tt < 4; ++tt) {
    int t0 = 16*tt + 4*lg;
    float4 cf4 = *(const float4*)(cfL + hh*256 + t0*4);
    uint2 wv;
    wv.x = pk2(cf4.x*xg[tt][0], cf4.y*xg[tt][1]);
    wv.y = pk2(cf4.z*xg[tt][2], cf4.w*xg[tt][3]);
    *(uint2*)(Xp + c15*128 + ((t0*2) ^ ((c15&7)<<4))) = wv;
  }
  __builtin_amdgcn_wave_barrier();
  __builtin_amdgcn_sched_barrier(0x7F);

  // ---- Cg export (before M overlays uC) ----
  { short8 ca = *(const short8*)(uC + lane*32);
    short8 cb = *(const short8*)(uC + lane*32 + 16);
    *(short8*)(Cg + cg*1024 + lane*16)     = ca;
    *(short8*)(Cg + cg*1024 + lane*16 + 8) = cb; }

  // ---- Sc MFMA ----
  { f32x4 sacc = zero4;
    #pragma unroll
    for (int kb = 0; kb < 2; ++kb) {
      int cb2 = (64*kb + 16*lg) ^ ((c15&7)<<4);
      short8 Afx = *(const short8*)(Xp + c15*128 + cb2);
      short8 Bfx = *(const short8*)(BT + c15*128 + cb2);
      sacc = __builtin_amdgcn_mfma_f32_16x16x32_bf16(Afx, Bfx, sacc, 0,0,0);
    }
    float cee = (lg < 2) ? cee0 : cee1;
    #pragma unroll
    for (int r = 0; r < 4; ++r)
      Sc[cg*256 + (4*lg+r)*16 + c15] = cee*sacc[r];
  }

  // ---- fragments for the M dance ----
  short8 Cfr[4], Bfr[4], Xf[2];
  #pragma unroll
  for (int tt = 0; tt < 4; ++tt) {
    Cfr[tt] = zero8; Bfr[tt] = zero8;
    if (lg < 2) {
      Cfr[tt] = *(const short8*)(uC + (16*tt + c15)*32 + 16*lg);
      Bfr[tt] = *(const short8*)(uB + (16*tt + c15)*32 + 16*lg);
    }
  }
  #pragma unroll
  for (int kb = 0; kb < 2; ++kb)
    Xf[kb] = *(const short8*)(Xp + c15*128 + ((64*kb + 16*lg) ^ ((c15&7)<<4)));
  __builtin_amdgcn_wave_barrier();
  __builtin_amdgcn_sched_barrier(0x7F);

  // ---- M = mask(B·C^T) bf16 swizzled (overlays BT/uB/uC) ----
  #pragma unroll
  for (int tt = 0; tt < 4; ++tt) {
    int t  = 16*tt + c15;
    int sw = (t&7)<<4;
    #pragma unroll
    for (int ts = 0; ts < 4; ++ts) {
      if (ts <= tt) {
        f32x4 gA = __builtin_amdgcn_mfma_f32_16x16x32_bf16(Bfr[ts], Cfr[tt], zero4, 0,0,0);
        if (ts == tt) {
          #pragma unroll
          for (int r = 0; r < 4; ++r)
            gA[r] = (4*lg + r <= c15) ? gA[r] : 0.f;
        }
        uint2 wv; wv.x = pk2(gA[0],gA[1]); wv.y = pk2(gA[2],gA[3]);
        *(uint2*)(Mb + t*128 + ((32*ts + 8*lg) ^ sw)) = wv;
      }
    }
    if (tt == 0 || tt == 2) {
      uint2 zv; zv.x = 0u; zv.y = 0u;
      *(uint2*)(Mb + t*128 + ((32*(tt+1) + 8*lg) ^ sw)) = zv;
    }
  }
  __builtin_amdgcn_wave_barrier();
  __builtin_amdgcn_sched_barrier(0x7F);

  // ---- Y_intra = M·X' ----
  f32x4 acc[4];
  #pragma unroll
  for (int tt = 0; tt < 4; ++tt) acc[tt] = zero4;
  #pragma unroll
  for (int tt = 0; tt < 4; ++tt) {
    int t = 16*tt + c15, sw = (t&7)<<4;
    { short8 Mf = *(const short8*)(Mb + t*128 + ((16*lg) ^ sw));
      acc[tt] = __builtin_amdgcn_mfma_f32_16x16x32_bf16(Mf, Xf[0], acc[tt], 0,0,0); }
    if (tt >= 2) {
      short8 Mf = *(const short8*)(Mb + t*128 + ((64 + 16*lg) ^ sw));
      acc[tt] = __builtin_amdgcn_mfma_f32_16x16x32_bf16(Mf, Xf[1], acc[tt], 0,0,0);
    }
  }
  __builtin_amdgcn_sched_barrier(0x7F);

  // ---- merge ce, + D*x (same fragment layout) -> ytr (overlays M) ----
  float Dh = (c15 < 8) ? s_misc[4] : s_misc[5];
  #pragma unroll
  for (int tt = 0; tt < 4; ++tt) {
    int t0 = 16*tt + 4*lg;
    float4 ce4 = *(const float4*)(ceL + hh*256 + t0*4);
    *(float*)(ytr + (t0  )*96 + c15*4) = ce4.x*acc[tt][0] + Dh*xg[tt][0];
    *(float*)(ytr + (t0+1)*96 + c15*4) = ce4.y*acc[tt][1] + Dh*xg[tt][1];
    *(float*)(ytr + (t0+2)*96 + c15*4) = ce4.z*acc[tt][2] + Dh*xg[tt][2];
    *(float*)(ytr + (t0+3)*96 + c15*4) = ce4.w*acc[tt][3] + Dh*xg[tt][3];
  }
  __builtin_amdgcn_wave_barrier();
  __builtin_amdgcn_sched_barrier(0x7F);

  // ---- Yg store (lane = t, coalesced 64B/lane) ----
  float* yg = Yg + cg*1024 + lane*16;
  #pragma unroll
  for (int i = 0; i < 4; ++i) {
    float4 q = *(const float4*)(ytr + lane*96 + i*16);
    *(float4*)(yg + 4*i) = q;
  }
}

__global__ __launch_bounds__(256) void k_scan(
    const float* __restrict__ Sc, const float* __restrict__ Pc,
    float* __restrict__ Stin)
{
  int b = blockIdx.x;
  int tid = threadIdx.x;           // hp*16 + n
  int h = tid >> 7;
  float st = 0.f;
  long base = (long)b * NCH;
  #pragma unroll 8
  for (int c = 0; c < NCH; ++c) {
    Stin[(base + c)*256 + tid] = st;
    st = st * Pc[(base + c)*2 + h] + Sc[(base + c)*256 + tid];
  }
}

// k_apply: y = Yg + ce*(C . St^T), then gate/RMS/out-proj/residual -> gf.
__global__ __launch_bounds__(256) void k_apply(
    const float* __restrict__ g0, const float* __restrict__ w_in,
    const float* __restrict__ norm_w, const float* __restrict__ w_out,
    const float* __restrict__ Stin, const float* __restrict__ ceg,
    const unsigned short* __restrict__ Cg, const float* __restrict__ Yg,
    float* __restrict__ gf)
{
  __shared__ float s_win[16][8];
  __shared__ float s_wout[8][16];
  __shared__ float s_nw[16];
  __shared__ float s_st[4][256];

  int tid = threadIdx.x, lane = tid & 63, wave = tid >> 6;
  if (tid < 128) s_win[tid>>3][tid&7] = w_in[tid];
  if (tid < 128) s_wout[tid>>4][tid&15] = w_out[tid];
  if (tid < 16)  s_nw[tid] = norm_w[tid];
  __syncthreads();

  auto dot8 = [&](const float* uu, int row) -> float {
    const float4* wr = (const float4*)s_win[row];
    float4 w0 = wr[0], w1 = wr[1];
    return uu[0]*w0.x + uu[1]*w0.y + uu[2]*w0.z + uu[3]*w0.w
         + uu[4]*w1.x + uu[5]*w1.y + uu[6]*w1.z + uu[7]*w1.w;
  };

  int b   = blockIdx.x >> 6;
  int chB = (blockIdx.x & 63)*4 + wave;
  long cg = (long)b*NCH + chB;
  long pos = (long)b*SL + chB*CQ + lane;

  { float4 t4 = *(const float4*)(Stin + cg*256 + lane*4);
    *(float4*)&s_st[wave][lane*4] = t4; }

  float u[8];
  { const float* up = g0 + pos*8;
    float4 a = *(const float4*)up, c = *(const float4*)(up+4);
    u[0]=a.x;u[1]=a.y;u[2]=a.z;u[3]=a.w;u[4]=c.x;u[5]=c.y;u[6]=c.z;u[7]=c.w; }

  float Cr[16];
  { const uint4* cp = (const uint4*)(Cg + cg*1024 + lane*16);
    uint4 ca = cp[0], cb = cp[1];
    Cr[0]=blo(ca.x); Cr[1]=bhi(ca.x); Cr[2]=blo(ca.y); Cr[3]=bhi(ca.y);
    Cr[4]=blo(ca.z); Cr[5]=bhi(ca.z); Cr[6]=blo(ca.w); Cr[7]=bhi(ca.w);
    Cr[8]=blo(cb.x); Cr[9]=bhi(cb.x); Cr[10]=blo(cb.y); Cr[11]=bhi(cb.y);
    Cr[12]=blo(cb.z); Cr[13]=bhi(cb.z); Cr[14]=blo(cb.w); Cr[15]=bhi(cb.w); }

  float yr[16];
  { const float* yp = Yg + cg*1024 + lane*16;
    #pragma unroll
    for (int i = 0; i < 4; ++i) {
      float4 q = *(const float4*)(yp + 4*i);
      yr[4*i]=q.x; yr[4*i+1]=q.y; yr[4*i+2]=q.z; yr[4*i+3]=q.w;
    } }
  float ce0t = ceg[cg*128 + lane];
  float ce1t = ceg[cg*128 + 64 + lane];

  __builtin_amdgcn_wave_barrier();
  __builtin_amdgcn_sched_barrier(0x7F);

  const float* st = &s_st[wave][0];
  float y[16];
  #pragma unroll
  for (int hp = 0; hp < 16; ++hp) {
    const float4* sp = (const float4*)(st + hp*16);
    float4 s0 = sp[0], s1 = sp[1], s2 = sp[2], s3 = sp[3];
    float a = Cr[0]*s0.x + Cr[1]*s0.y + Cr[2]*s0.z + Cr[3]*s0.w
            + Cr[4]*s1.x + Cr[5]*s1.y + Cr[6]*s1.z + Cr[7]*s1.w
            + Cr[8]*s2.x + Cr[9]*s2.y + Cr[10]*s2.z + Cr[11]*s2.w
            + Cr[12]*s3.x + Cr[13]*s3.y + Cr[14]*s3.z + Cr[15]*s3.w;
    y[hp] = yr[hp] + ((hp < 8) ? ce0t : ce1t)*a;
  }

  float yv[16]; float ss = 0.f;
  #pragma unroll
  for (int d = 0; d < 16; ++d) {
    float zz = dot8(u, d);
    float v = y[d] * (zz * sigu(zz));
    yv[d] = v; ss += v*v;
  }
  float scn = rsqrtf(ss*(1.f/16.f) + 1e-5f);
  { const float4* nw = (const float4*)s_nw;
    float4 n0 = nw[0], n1 = nw[1], n2 = nw[2], n3 = nw[3];
    yv[0]*=scn*n0.x; yv[1]*=scn*n0.y; yv[2]*=scn*n0.z; yv[3]*=scn*n0.w;
    yv[4]*=scn*n1.x; yv[5]*=scn*n1.y; yv[6]*=scn*n1.z; yv[7]*=scn*n1.w;
    yv[8]*=scn*n2.x; yv[9]*=scn*n2.y; yv[10]*=scn*n2.z; yv[11]*=scn*n2.w;
    yv[12]*=scn*n3.x; yv[13]*=scn*n3.y; yv[14]*=scn*n3.z; yv[15]*=scn*n3.w; }
  float og[8];
  #pragma unroll
  for (int g = 0; g < 8; ++g) {
    const float4* wr = (const float4*)s_wout[g];
    float4 w0 = wr[0], w1 = wr[1], w2 = wr[2], w3 = wr[3];
    float a = u[g];
    a += yv[0]*w0.x + yv[1]*w0.y + yv[2]*w0.z + yv[3]*w0.w;
    a += yv[4]*w1.x + yv[5]*w1.y + yv[6]*w1.z + yv[7]*w1.w;
    a += yv[8]*w2.x + yv[9]*w2.y + yv[10]*w2.z + yv[11]*w2.w;
    a += yv[12]*w3.x + yv[13]*w3.y + yv[14]*w3.z + yv[15]*w3.w;
    og[g] = a;
  }
  float* gp = gf + pos*8;
  *(float4*)gp     = make_float4(og[0],og[1],og[2],og[3]);
  *(float4*)(gp+4) = make_float4(og[4],og[5],og[6],og[7]);
}

__global__ __launch_bounds__(256) void k_detok(
    const float* __restrict__ x, const float* __restrict__ gf,
    const float* __restrict__ w_detok, const float* __restrict__ b_detok,
    float* __restrict__ out)
{
  __shared__ float s_wd[NC][8];
  __shared__ float s_bd[NC];
  for (int i = threadIdx.x; i < NC*8; i += 256) s_wd[i>>3][i&7] = w_detok[i];
  if (threadIdx.x < NC) s_bd[threadIdx.x] = b_detok[threadIdx.x];
  __syncthreads();
  long idx = (long)blockIdx.x * 256 + threadIdx.x;
  int b = (int)(idx >> 14);
  int l = (int)(idx & (SL-1));
  float gv[8];
  const float* gp = gf + idx*8;
  { float4 a = *(const float4*)gp, c = *(const float4*)(gp+4);
    gv[0]=a.x;gv[1]=a.y;gv[2]=a.z;gv[3]=a.w;gv[4]=c.x;gv[5]=c.y;gv[6]=c.z;gv[7]=c.w; }
  const float* xp = x + (long)b*NC*HW + l;
  float* op = out + (long)b*NC*HW + l;
  #pragma unroll 4
  for (int c = 0; c < NC; ++c) {
    const float4* wr = (const float4*)s_wd[c];
    float4 w0 = wr[0], w1 = wr[1];
    float a = s_bd[c] + xp[(long)c*HW];
    a += gv[0]*w0.x + gv[1]*w0.y + gv[2]*w0.z + gv[3]*w0.w;
    a += gv[4]*w1.x + gv[5]*w1.y + gv[6]*w1.z + gv[7]*w1.w;
    op[(long)c*HW] = a;
  }
}
} // namespace

extern "C" void kernel_launch(void* const* d_in, const int* in_sizes, int n_in,
                              void* d_out, int out_size, void* d_ws, size_t ws_size,
                              hipStream_t stream)
{
  const float* x       = (const float*)d_in[0];
  const float* w_tok   = (const float*)d_in[1];
  const float* b_tok   = (const float*)d_in[2];
  const float* w_detok = (const float*)d_in[3];
  const float* b_detok = (const float*)d_in[4];
  const float* w_in    = (const float*)d_in[5];
  const float* w_conv  = (const float*)d_in[6];
  const float* b_conv  = (const float*)d_in[7];
  const float* dt_bias = (const float*)d_in[8];
  const float* A_log   = (const float*)d_in[9];
  const float* Dvec    = (const float*)d_in[10];
  const float* norm_w  = (const float*)d_in[11];
  const float* w_out   = (const float*)d_in[12];
  float* out = (float*)d_out;

  float* ws   = (float*)d_ws;
  float* g0   = ws;                          // 2,097,152 f
  float* gf   = g0 + (long)NB*SL*8;          // 2,097,152 f
  float* Sc   = gf + (long)NB*SL*8;          // 1,048,576 f
  float* Pc   = Sc + (long)NB*NCH*256;       // 8,192 f
  float* Stin = Pc + (long)NB*NCH*2;         // 1,048,576 f
  float* ceg  = Stin + (long)NB*NCH*256;     // 524,288 f
  float* Yg   = ceg + (long)NB*NCH*128;      // 4,194,304 f
  unsigned short* Cg = (unsigned short*)(Yg + (long)NB*NCH*1024);  // 8 MB

  k_tok<<<NB*SL/256, 256, 0, stream>>>(x, w_tok, b_tok, g0);
  k_front<<<NB*NCH/4, 256, 0, stream>>>(g0, w_in, w_conv, b_conv, dt_bias,
                                        A_log, Dvec, Sc, Pc, ceg, Cg, Yg);
  k_scan<<<NB, 256, 0, stream>>>(Sc, Pc, Stin);
  k_apply<<<NB*NCH/4, 256, 0, stream>>>(g0, w_in, norm_w, w_out,
                                        Stin, ceg, Cg, Yg, gf);
  k_detok<<<NB*SL/256, 256, 0, stream>>>(x, gf, w_detok, b_detok, out);
}

// Round 11
// 94.179 us; speedup vs baseline: 1.2843x; 1.0818x over previous
//
#include <hip/hip_runtime.h>

namespace {
constexpr int NB   = 16;
constexpr int NC   = 64;
constexpr int HW   = 128*128;
constexpr int SL   = 16384;
constexpr int CQ   = 64;
constexpr int NCH  = SL/CQ;   // 256
constexpr int PWV  = 9728;    // per-wave LDS bytes in k_front

typedef short short8 __attribute__((ext_vector_type(8)));   // 8 bf16
typedef float f32x4  __attribute__((ext_vector_type(4)));

__device__ __forceinline__ float frcp(float x){ return __builtin_amdgcn_rcpf(x); }
__device__ __forceinline__ float rl(float v, int s){
  return __int_as_float(__builtin_amdgcn_readlane(__float_as_int(v), s));
}
__device__ __forceinline__ float sigu(float a){ return frcp(1.0f + __expf(-a)); }
__device__ __forceinline__ float softplusf(float a){
  return fmaxf(a, 0.f) + __logf(1.f + __expf(-fabsf(a)));
}
__device__ __forceinline__ unsigned bfr(float x){
  unsigned u = __float_as_uint(x);
  u = u + 0x7FFF + ((u>>16)&1);
  return u>>16;
}
__device__ __forceinline__ unsigned pk2(float a, float b){
  return (bfr(a)&0xFFFFu) | (bfr(b)<<16);
}
__device__ __forceinline__ float blo(unsigned u){ return __uint_as_float(u<<16); }
__device__ __forceinline__ float bhi(unsigned u){ return __uint_as_float(u & 0xFFFF0000u); }
union CV8 { unsigned u[4]; short8 s; };

// k_tok: tokenize; block 0 additionally builds the fused conv∘in-proj weight
// table Weff (bf16 [64][32]) in global for k_front.
__global__ __launch_bounds__(256) void k_tok(
    const float* __restrict__ x, const float* __restrict__ w_tok,
    const float* __restrict__ b_tok, float* __restrict__ g0,
    const float* __restrict__ w_in, const float* __restrict__ w_conv,
    unsigned short* __restrict__ weff)
{
  if (blockIdx.x == 0) {
    for (int i = threadIdx.x; i < 64*32; i += 256) {
      int j = i >> 5, k = i & 31;
      float v = 0.f;
      if (j < 48) {
        if (k < 24) v = w_conv[j*3 + (k>>3)] * w_in[(16+j)*8 + (k&7)];
      } else if (j < 50) {
        if (k >= 16 && k < 24) v = w_in[(64 + (j-48))*8 + (k-16)];
      }
      weff[i] = (unsigned short)bfr(v);
    }
  }
  __shared__ float s_wt[NC][8];
  __shared__ float s_bt[8];
  for (int i = threadIdx.x; i < NC*8; i += 256) s_wt[i>>3][i&7] = w_tok[(i&7)*NC + (i>>3)];
  if (threadIdx.x < 8) s_bt[threadIdx.x] = b_tok[threadIdx.x];
  __syncthreads();
  long idx = (long)blockIdx.x * 256 + threadIdx.x;
  int b = (int)(idx >> 14);
  int l = (int)(idx & (SL-1));
  float acc[8];
  #pragma unroll
  for (int g = 0; g < 8; ++g) acc[g] = s_bt[g];
  const float* xp = x + (long)b*NC*HW + l;
  #pragma unroll 8
  for (int c = 0; c < NC; ++c) {
    float v = xp[(long)c*HW];
    const float4* wr = (const float4*)s_wt[c];
    float4 w0 = wr[0], w1 = wr[1];
    acc[0] += v*w0.x; acc[1] += v*w0.y; acc[2] += v*w0.z; acc[3] += v*w0.w;
    acc[4] += v*w1.x; acc[5] += v*w1.y; acc[6] += v*w1.z; acc[7] += v*w1.w;
  }
  float* gp = g0 + idx*8;
  *(float4*)gp     = make_float4(acc[0],acc[1],acc[2],acc[3]);
  *(float4*)(gp+4) = make_float4(acc[4],acc[5],acc[6],acc[7]);
}

// k_front: fused (conv ∘ in-proj) via MFMA (Weff from global), then
// Sc/Pc + masked decay matrix M + Y_intra (+D*x), one wave per chunk.
__global__ __launch_bounds__(256) void k_front(
    const float* __restrict__ g0, const unsigned short* __restrict__ weff,
    const float* __restrict__ b_conv,
    const float* __restrict__ dt_bias, const float* __restrict__ A_log,
    const float* __restrict__ Dvec,
    float* __restrict__ Sc, float* __restrict__ Pc,
    float* __restrict__ ceg, unsigned short* __restrict__ Cg,
    float* __restrict__ Yg)
{
  __shared__ float s_bc[48];
  __shared__ float s_misc[8];       // A0,A1,dtb0,dtb1,D0,D1
  __shared__ char  s_wv[4][PWV];
  // per-wave: BT 0..2K | uB 2K..4K | uC 4K..6K | Xp 6K..8K
  // overlays: M 0..8K (after BT/uB/uC/Xp consumed), ytr 0..6K (after M)
  // dtL 8192 | cfL 8704 | ceL 9216  (f32[2][64] each)

  int tid = threadIdx.x, lane = tid & 63, wave = tid >> 6;
  int c15 = lane & 15, lg = lane >> 4;

  if (tid < 48) s_bc[tid] = b_conv[tid];
  if (tid < 2) {
    s_misc[tid]   = -__expf(A_log[tid]);
    s_misc[2+tid] = dt_bias[tid];
    s_misc[4+tid] = Dvec[tid];
  }
  __syncthreads();

  int b   = blockIdx.x >> 6;                 // 64 blocks/batch, 4 chunks/block
  int chB = (blockIdx.x & 63)*4 + wave;
  long cg = (long)b*NCH + chB;
  int l0  = chB*CQ;
  char* WR = s_wv[wave];
  char* BT  = WR;
  char* uB  = WR + 2048;
  char* uC  = WR + 4096;
  char* Xp  = WR + 6144;
  char* Mb  = WR;          // overlay after BT/uB/uC/Xp consumed
  char* ytr = WR;          // overlay after M consumed ([64][24] f32)
  char* dtL = WR + 8192;   // f32 [2][64]
  char* cfL = WR + 8704;   // f32 [2][64]
  char* ceL = WR + 9216;   // f32 [2][64]

  short8 zero8 = {0,0,0,0,0,0,0,0};
  f32x4  zero4 = {0.f,0.f,0.f,0.f};

  // ---- A-fragments: rows t = 16tt+c15, k = lg*8+g -> u[t-2+lg][g] ----
  short8 Af[4];
  #pragma unroll
  for (int tt = 0; tt < 4; ++tt) {
    int p = l0 + 16*tt + c15 - 2 + lg;
    bool ok = (lg < 3) && (p >= 0);
    const float* up = g0 + ((long)b*SL + (ok ? p : 0))*8;
    float4 a = *(const float4*)up, c = *(const float4*)(up+4);
    CV8 w;
    w.u[0] = pk2(a.x,a.y); w.u[1] = pk2(a.z,a.w);
    w.u[2] = pk2(c.x,c.y); w.u[3] = pk2(c.z,c.w);
    Af[tt] = ok ? w.s : zero8;
  }

  // ---- fused in-proj+conv MFMAs, per col-tile jj (Weff from global/L2) ----
  f32x4 xg[4];
  #pragma unroll
  for (int jj = 0; jj < 4; ++jj) {
    short8 Wf = *(const short8*)(weff + (16*jj + c15)*32 + lg*8);
    f32x4 o[4];
    #pragma unroll
    for (int tt = 0; tt < 4; ++tt)
      o[tt] = __builtin_amdgcn_mfma_f32_16x16x32_bf16(Af[tt], Wf, zero4, 0,0,0);
    if (jj == 3) {
      if (c15 < 2) {
        float bias = s_misc[2+c15];
        #pragma unroll
        for (int tt = 0; tt < 4; ++tt) {
          #pragma unroll
          for (int r = 0; r < 4; ++r)
            *(float*)(dtL + c15*256 + (16*tt + 4*lg + r)*4) = o[tt][r] + bias;
        }
      }
    } else {
      float bias = s_bc[16*jj + c15];
      #pragma unroll
      for (int tt = 0; tt < 4; ++tt) {
        float s0 = (o[tt][0]+bias), s1 = (o[tt][1]+bias);
        float s2 = (o[tt][2]+bias), s3 = (o[tt][3]+bias);
        s0 *= sigu(s0); s1 *= sigu(s1); s2 *= sigu(s2); s3 *= sigu(s3);
        int t0 = 16*tt + 4*lg;
        if (jj == 0) {
          f32x4 v; v[0]=s0; v[1]=s1; v[2]=s2; v[3]=s3;
          xg[tt] = v;
        } else if (jj == 1) {
          uint2 wv; wv.x = pk2(s0,s1); wv.y = pk2(s2,s3);
          *(uint2*)(BT + c15*128 + ((t0*2) ^ ((c15&7)<<4))) = wv;
          *(short*)(uB + (t0  )*32 + c15*2) = (short)bfr(s0);
          *(short*)(uB + (t0+1)*32 + c15*2) = (short)bfr(s1);
          *(short*)(uB + (t0+2)*32 + c15*2) = (short)bfr(s2);
          *(short*)(uB + (t0+3)*32 + c15*2) = (short)bfr(s3);
        } else {
          *(short*)(uC + (t0  )*32 + c15*2) = (short)bfr(s0);
          *(short*)(uC + (t0+1)*32 + c15*2) = (short)bfr(s1);
          *(short*)(uC + (t0+2)*32 + c15*2) = (short)bfr(s2);
          *(short*)(uC + (t0+3)*32 + c15*2) = (short)bfr(s3);
        }
      }
    }
  }
  __builtin_amdgcn_wave_barrier();
  __builtin_amdgcn_sched_barrier(0x7F);

  // ---- dt softplus + prefix cumsum (per lane = t) ----
  float dt0 = softplusf(*(const float*)(dtL + lane*4));
  float dt1 = softplusf(*(const float*)(dtL + 256 + lane*4));
  float c0 = s_misc[0]*dt0, c1 = s_misc[1]*dt1;
  #pragma unroll
  for (int off = 1; off < 64; off <<= 1) {
    float t0 = __shfl_up(c0, off), t1 = __shfl_up(c1, off);
    if (lane >= off) { c0 += t0; c1 += t1; }
  }
  float ce0 = __expf(c0), ce1 = __expf(c1);
  float cf0 = __expf(-c0)*dt0, cf1 = __expf(-c1)*dt1;
  float cee0 = rl(ce0, 63), cee1 = rl(ce1, 63);
  ceg[cg*128 + lane]      = ce0;
  ceg[cg*128 + 64 + lane] = ce1;
  if (lane == 0) { Pc[cg*2] = cee0; Pc[cg*2+1] = cee1; }
  *(float*)(cfL + lane*4)       = cf0;
  *(float*)(cfL + 256 + lane*4) = cf1;
  *(float*)(ceL + lane*4)       = ce0;
  *(float*)(ceL + 256 + lane*4) = ce1;
  __builtin_amdgcn_wave_barrier();
  __builtin_amdgcn_sched_barrier(0x7F);

  // ---- X' slab: X'[hp=c15][t] = cf_h[t]*x[t][hp], bf16 swizzled ----
  int hh = (c15 < 8) ? 0 : 1;
  #pragma unroll
  for (int tt = 0; tt < 4; ++tt) {
    int t0 = 16*tt + 4*lg;
    float4 cf4 = *(const float4*)(cfL + hh*256 + t0*4);
    uint2 wv;
    wv.x = pk2(cf4.x*xg[tt][0], cf4.y*xg[tt][1]);
    wv.y = pk2(cf4.z*xg[tt][2], cf4.w*xg[tt][3]);
    *(uint2*)(Xp + c15*128 + ((t0*2) ^ ((c15&7)<<4))) = wv;
  }
  __builtin_amdgcn_wave_barrier();
  __builtin_amdgcn_sched_barrier(0x7F);

  // ---- Cg export (before M overlays uC) ----
  { short8 ca = *(const short8*)(uC + lane*32);
    short8 cb = *(const short8*)(uC + lane*32 + 16);
    *(short8*)(Cg + cg*1024 + lane*16)     = ca;
    *(short8*)(Cg + cg*1024 + lane*16 + 8) = cb; }

  // ---- Sc MFMA ----
  { f32x4 sacc = zero4;
    #pragma unroll
    for (int kb = 0; kb < 2; ++kb) {
      int cb2 = (64*kb + 16*lg) ^ ((c15&7)<<4);
      short8 Afx = *(const short8*)(Xp + c15*128 + cb2);
      short8 Bfx = *(const short8*)(BT + c15*128 + cb2);
      sacc = __builtin_amdgcn_mfma_f32_16x16x32_bf16(Afx, Bfx, sacc, 0,0,0);
    }
    float cee = (lg < 2) ? cee0 : cee1;
    #pragma unroll
    for (int r = 0; r < 4; ++r)
      Sc[cg*256 + (4*lg+r)*16 + c15] = cee*sacc[r];
  }

  // ---- fragments for the M dance ----
  short8 Cfr[4], Bfr[4], Xf[2];
  #pragma unroll
  for (int tt = 0; tt < 4; ++tt) {
    Cfr[tt] = zero8; Bfr[tt] = zero8;
    if (lg < 2) {
      Cfr[tt] = *(const short8*)(uC + (16*tt + c15)*32 + 16*lg);
      Bfr[tt] = *(const short8*)(uB + (16*tt + c15)*32 + 16*lg);
    }
  }
  #pragma unroll
  for (int kb = 0; kb < 2; ++kb)
    Xf[kb] = *(const short8*)(Xp + c15*128 + ((64*kb + 16*lg) ^ ((c15&7)<<4)));
  __builtin_amdgcn_wave_barrier();
  __builtin_amdgcn_sched_barrier(0x7F);

  // ---- M = mask(B·C^T) bf16 swizzled (overlays BT/uB/uC/Xp) ----
  #pragma unroll
  for (int tt = 0; tt < 4; ++tt) {
    int t  = 16*tt + c15;
    int sw = (t&7)<<4;
    #pragma unroll
    for (int ts = 0; ts < 4; ++ts) {
      if (ts <= tt) {
        f32x4 gA = __builtin_amdgcn_mfma_f32_16x16x32_bf16(Bfr[ts], Cfr[tt], zero4, 0,0,0);
        if (ts == tt) {
          #pragma unroll
          for (int r = 0; r < 4; ++r)
            gA[r] = (4*lg + r <= c15) ? gA[r] : 0.f;
        }
        uint2 wv; wv.x = pk2(gA[0],gA[1]); wv.y = pk2(gA[2],gA[3]);
        *(uint2*)(Mb + t*128 + ((32*ts + 8*lg) ^ sw)) = wv;
      }
    }
    if (tt == 0 || tt == 2) {
      uint2 zv; zv.x = 0u; zv.y = 0u;
      *(uint2*)(Mb + t*128 + ((32*(tt+1) + 8*lg) ^ sw)) = zv;
    }
  }
  __builtin_amdgcn_wave_barrier();
  __builtin_amdgcn_sched_barrier(0x7F);

  // ---- Y_intra = M·X' ----
  f32x4 acc[4];
  #pragma unroll
  for (int tt = 0; tt < 4; ++tt) acc[tt] = zero4;
  #pragma unroll
  for (int tt = 0; tt < 4; ++tt) {
    int t = 16*tt + c15, sw = (t&7)<<4;
    { short8 Mf = *(const short8*)(Mb + t*128 + ((16*lg) ^ sw));
      acc[tt] = __builtin_amdgcn_mfma_f32_16x16x32_bf16(Mf, Xf[0], acc[tt], 0,0,0); }
    if (tt >= 2) {
      short8 Mf = *(const short8*)(Mb + t*128 + ((64 + 16*lg) ^ sw));
      acc[tt] = __builtin_amdgcn_mfma_f32_16x16x32_bf16(Mf, Xf[1], acc[tt], 0,0,0);
    }
  }
  __builtin_amdgcn_sched_barrier(0x7F);

  // ---- merge ce, + D*x (same fragment layout) -> ytr (overlays M) ----
  float Dh = (c15 < 8) ? s_misc[4] : s_misc[5];
  #pragma unroll
  for (int tt = 0; tt < 4; ++tt) {
    int t0 = 16*tt + 4*lg;
    float4 ce4 = *(const float4*)(ceL + hh*256 + t0*4);
    *(float*)(ytr + (t0  )*96 + c15*4) = ce4.x*acc[tt][0] + Dh*xg[tt][0];
    *(float*)(ytr + (t0+1)*96 + c15*4) = ce4.y*acc[tt][1] + Dh*xg[tt][1];
    *(float*)(ytr + (t0+2)*96 + c15*4) = ce4.z*acc[tt][2] + Dh*xg[tt][2];
    *(float*)(ytr + (t0+3)*96 + c15*4) = ce4.w*acc[tt][3] + Dh*xg[tt][3];
  }
  __builtin_amdgcn_wave_barrier();
  __builtin_amdgcn_sched_barrier(0x7F);

  // ---- Yg store (lane = t, coalesced 64B/lane) ----
  float* yg = Yg + cg*1024 + lane*16;
  #pragma unroll
  for (int i = 0; i < 4; ++i) {
    float4 q = *(const float4*)(ytr + lane*96 + i*16);
    *(float4*)(yg + 4*i) = q;
  }
}

__global__ __launch_bounds__(256) void k_scan(
    const float* __restrict__ Sc, const float* __restrict__ Pc,
    float* __restrict__ Stin)
{
  int b = blockIdx.x;
  int tid = threadIdx.x;           // hp*16 + n
  int h = tid >> 7;
  float st = 0.f;
  long base = (long)b * NCH;
  #pragma unroll 8
  for (int c = 0; c < NCH; ++c) {
    Stin[(base + c)*256 + tid] = st;
    st = st * Pc[(base + c)*2 + h] + Sc[(base + c)*256 + tid];
  }
}

// k_out: fused apply + detok.  y = Yg + ce*(C.St^T) -> gate/RMS/out-proj/+u
// -> og, then out[c] = x[c] + og.w_detok[c] + b_detok[c] directly (gf removed).
__global__ __launch_bounds__(256) void k_out(
    const float* __restrict__ g0, const float* __restrict__ w_in,
    const float* __restrict__ norm_w, const float* __restrict__ w_out,
    const float* __restrict__ Stin, const float* __restrict__ ceg,
    const unsigned short* __restrict__ Cg, const float* __restrict__ Yg,
    const float* __restrict__ x, const float* __restrict__ w_detok,
    const float* __restrict__ b_detok, float* __restrict__ out)
{
  __shared__ float s_win[16][8];
  __shared__ float s_wout[8][16];
  __shared__ float s_nw[16];
  __shared__ float s_wd[NC][8];
  __shared__ float s_bd[NC];
  __shared__ float s_st[4][256];

  int tid = threadIdx.x, lane = tid & 63, wave = tid >> 6;
  if (tid < 128) s_win[tid>>3][tid&7] = w_in[tid];
  if (tid < 128) s_wout[tid>>4][tid&15] = w_out[tid];
  if (tid < 16)  s_nw[tid] = norm_w[tid];
  for (int i = tid; i < NC*8; i += 256) s_wd[i>>3][i&7] = w_detok[i];
  if (tid < NC) s_bd[tid] = b_detok[tid];
  __syncthreads();

  auto dot8 = [&](const float* uu, int row) -> float {
    const float4* wr = (const float4*)s_win[row];
    float4 w0 = wr[0], w1 = wr[1];
    return uu[0]*w0.x + uu[1]*w0.y + uu[2]*w0.z + uu[3]*w0.w
         + uu[4]*w1.x + uu[5]*w1.y + uu[6]*w1.z + uu[7]*w1.w;
  };

  int b   = blockIdx.x >> 6;
  int chB = (blockIdx.x & 63)*4 + wave;
  long cg = (long)b*NCH + chB;
  int l   = chB*CQ + lane;
  long pos = (long)b*SL + l;

  { float4 t4 = *(const float4*)(Stin + cg*256 + lane*4);
    *(float4*)&s_st[wave][lane*4] = t4; }

  float u[8];
  { const float* up = g0 + pos*8;
    float4 a = *(const float4*)up, c = *(const float4*)(up+4);
    u[0]=a.x;u[1]=a.y;u[2]=a.z;u[3]=a.w;u[4]=c.x;u[5]=c.y;u[6]=c.z;u[7]=c.w; }

  float Cr[16];
  { const uint4* cp = (const uint4*)(Cg + cg*1024 + lane*16);
    uint4 ca = cp[0], cb = cp[1];
    Cr[0]=blo(ca.x); Cr[1]=bhi(ca.x); Cr[2]=blo(ca.y); Cr[3]=bhi(ca.y);
    Cr[4]=blo(ca.z); Cr[5]=bhi(ca.z); Cr[6]=blo(ca.w); Cr[7]=bhi(ca.w);
    Cr[8]=blo(cb.x); Cr[9]=bhi(cb.x); Cr[10]=blo(cb.y); Cr[11]=bhi(cb.y);
    Cr[12]=blo(cb.z); Cr[13]=bhi(cb.z); Cr[14]=blo(cb.w); Cr[15]=bhi(cb.w); }

  float yr[16];
  { const float* yp = Yg + cg*1024 + lane*16;
    #pragma unroll
    for (int i = 0; i < 4; ++i) {
      float4 q = *(const float4*)(yp + 4*i);
      yr[4*i]=q.x; yr[4*i+1]=q.y; yr[4*i+2]=q.z; yr[4*i+3]=q.w;
    } }
  float ce0t = ceg[cg*128 + lane];
  float ce1t = ceg[cg*128 + 64 + lane];

  __builtin_amdgcn_wave_barrier();
  __builtin_amdgcn_sched_barrier(0x7F);

  const float* st = &s_st[wave][0];
  float y[16];
  #pragma unroll
  for (int hp = 0; hp < 16; ++hp) {
    const float4* sp = (const float4*)(st + hp*16);
    float4 s0 = sp[0], s1 = sp[1], s2 = sp[2], s3 = sp[3];
    float a = Cr[0]*s0.x + Cr[1]*s0.y + Cr[2]*s0.z + Cr[3]*s0.w
            + Cr[4]*s1.x + Cr[5]*s1.y + Cr[6]*s1.z + Cr[7]*s1.w
            + Cr[8]*s2.x + Cr[9]*s2.y + Cr[10]*s2.z + Cr[11]*s2.w
            + Cr[12]*s3.x + Cr[13]*s3.y + Cr[14]*s3.z + Cr[15]*s3.w;
    y[hp] = yr[hp] + ((hp < 8) ? ce0t : ce1t)*a;
  }

  float yv[16]; float ss = 0.f;
  #pragma unroll
  for (int d = 0; d < 16; ++d) {
    float zz = dot8(u, d);
    float v = y[d] * (zz * sigu(zz));
    yv[d] = v; ss += v*v;
  }
  float scn = rsqrtf(ss*(1.f/16.f) + 1e-5f);
  { const float4* nw = (const float4*)s_nw;
    float4 n0 = nw[0], n1 = nw[1], n2 = nw[2], n3 = nw[3];
    yv[0]*=scn*n0.x; yv[1]*=scn*n0.y; yv[2]*=scn*n0.z; yv[3]*=scn*n0.w;
    yv[4]*=scn*n1.x; yv[5]*=scn*n1.y; yv[6]*=scn*n1.z; yv[7]*=scn*n1.w;
    yv[8]*=scn*n2.x; yv[9]*=scn*n2.y; yv[10]*=scn*n2.z; yv[11]*=scn*n2.w;
    yv[12]*=scn*n3.x; yv[13]*=scn*n3.y; yv[14]*=scn*n3.z; yv[15]*=scn*n3.w; }
  float og[8];
  #pragma unroll
  for (int g = 0; g < 8; ++g) {
    const float4* wr = (const float4*)s_wout[g];
    float4 w0 = wr[0], w1 = wr[1], w2 = wr[2], w3 = wr[3];
    float a = u[g];
    a += yv[0]*w0.x + yv[1]*w0.y + yv[2]*w0.z + yv[3]*w0.w;
    a += yv[4]*w1.x + yv[5]*w1.y + yv[6]*w1.z + yv[7]*w1.w;
    a += yv[8]*w2.x + yv[9]*w2.y + yv[10]*w2.z + yv[11]*w2.w;
    a += yv[12]*w3.x + yv[13]*w3.y + yv[14]*w3.z + yv[15]*w3.w;
    og[g] = a;
  }

  // ---- detok fused: out[c] = x[c] + og.wd[c] + bd[c] ----
  const float* xp = x + (long)b*NC*HW + l;
  float* op = out + (long)b*NC*HW + l;
  #pragma unroll 4
  for (int c = 0; c < NC; ++c) {
    const float4* wr = (const float4*)s_wd[c];
    float4 w0 = wr[0], w1 = wr[1];
    float a = s_bd[c] + xp[(long)c*HW];
    a += og[0]*w0.x + og[1]*w0.y + og[2]*w0.z + og[3]*w0.w;
    a += og[4]*w1.x + og[5]*w1.y + og[6]*w1.z + og[7]*w1.w;
    op[(long)c*HW] = a;
  }
}
} // namespace

extern "C" void kernel_launch(void* const* d_in, const int* in_sizes, int n_in,
                              void* d_out, int out_size, void* d_ws, size_t ws_size,
                              hipStream_t stream)
{
  const float* x       = (const float*)d_in[0];
  const float* w_tok   = (const float*)d_in[1];
  const float* b_tok   = (const float*)d_in[2];
  const float* w_detok = (const float*)d_in[3];
  const float* b_detok = (const float*)d_in[4];
  const float* w_in    = (const float*)d_in[5];
  const float* w_conv  = (const float*)d_in[6];
  const float* b_conv  = (const float*)d_in[7];
  const float* dt_bias = (const float*)d_in[8];
  const float* A_log   = (const float*)d_in[9];
  const float* Dvec    = (const float*)d_in[10];
  const float* norm_w  = (const float*)d_in[11];
  const float* w_out   = (const float*)d_in[12];
  float* out = (float*)d_out;

  float* ws   = (float*)d_ws;
  float* g0   = ws;                          // 2,097,152 f
  float* Sc   = g0 + (long)NB*SL*8;          // 1,048,576 f
  float* Pc   = Sc + (long)NB*NCH*256;       // 8,192 f
  float* Stin = Pc + (long)NB*NCH*2;         // 1,048,576 f
  float* ceg  = Stin + (long)NB*NCH*256;     // 524,288 f
  float* Yg   = ceg + (long)NB*NCH*128;      // 4,194,304 f
  unsigned short* Cg = (unsigned short*)(Yg + (long)NB*NCH*1024);  // 8 MB
  unsigned short* weff = Cg + (long)NB*NCH*1024;                   // 4 KB

  k_tok<<<NB*SL/256, 256, 0, stream>>>(x, w_tok, b_tok, g0, w_in, w_conv, weff);
  k_front<<<NB*NCH/4, 256, 0, stream>>>(g0, weff, b_conv, dt_bias,
                                        A_log, Dvec, Sc, Pc, ceg, Cg, Yg);
  k_scan<<<NB, 256, 0, stream>>>(Sc, Pc, Stin);
  k_out<<<NB*NCH/4, 256, 0, stream>>>(g0, w_in, norm_w, w_out,
                                      Stin, ceg, Cg, Yg,
                                      x, w_detok, b_detok, out);
}